// Round 3
// baseline (1291.399 us; speedup 1.0000x reference)
//
#include <hip/hip_runtime.h>
#include <hip/hip_bf16.h>
#include <stdint.h>

// SelfAttentionBlock: B=4,S=4096,C=2048,O=2048,H=8,DH=256
// Inputs/outputs are FLOAT32 (per reference dtypes). Internal compute bf16 MFMA.
//
// Pipeline:
//   1) transpose+convert Wq/Wk/Wv/Wo (fp32 [K][N]) -> bf16 [N][K] in ws
//   2) q,k,v = x @ W + b   (fp32-A staging w/ cvt, bf16 MFMA, bf16 out)
//   3) per-position 8-head attention (wave/position), attended overwrites q
//   4) y = attended @ Wo + bo + x  -> d_out (fp32)
//   5) LayerNorm in place on d_out (fp32)
//
// ws: WqT(8M) WkT(8M) WvT(8M) WoT(8M) q(64M) k(64M) v(64M) = 224MB

using short8  = __attribute__((ext_vector_type(8))) short;
using floatx4 = __attribute__((ext_vector_type(4))) float;

__device__ __forceinline__ float bf2f(ushort u) {
    union { uint32_t i; float f; } v; v.i = ((uint32_t)u) << 16; return v.f;
}
__device__ __forceinline__ ushort f2bf(float f) {
    union { float f; uint32_t i; } v; v.f = f;
    uint32_t r = v.i + 0x7fffu + ((v.i >> 16) & 1u);
    return (ushort)(r >> 16);
}
__device__ __forceinline__ short8 pack8(const floatx4& a, const floatx4& b) {
    short8 o;
    o[0] = (short)f2bf(a[0]); o[1] = (short)f2bf(a[1]);
    o[2] = (short)f2bf(a[2]); o[3] = (short)f2bf(a[3]);
    o[4] = (short)f2bf(b[0]); o[5] = (short)f2bf(b[1]);
    o[6] = (short)f2bf(b[2]); o[7] = (short)f2bf(b[3]);
    return o;
}

// -------- weight transpose+convert: fp32 [2048][2048] -> bf16 [2048][2048]^T
__global__ void convT2048(const float* __restrict__ in, ushort* __restrict__ out) {
    __shared__ alignas(16) float tile[32][33];
    const int x = blockIdx.x * 32 + threadIdx.x;
    const int y0 = blockIdx.y * 32;
    for (int j = threadIdx.y; j < 32; j += 8)
        tile[j][threadIdx.x] = in[(size_t)(y0 + j) * 2048 + x];
    __syncthreads();
    const int x2 = blockIdx.y * 32 + threadIdx.x;
    const int y2 = blockIdx.x * 32;
    for (int j = threadIdx.y; j < 32; j += 8)
        out[(size_t)(y2 + j) * 2048 + x2] = f2bf(tile[threadIdx.x][j]);
}

// -------- GEMM: C[M][2048] = A[M][2048] @ Bt^T + bias (+resid) --------------
// Bt bf16 [N][K]. 128x128 tile, BK=32, 4 waves x (4x4) 16x16x32 MFMA.
// AT = float (cvt in staging) or ushort (bf16). CT = ushort (bf16) or float.
template <typename AT, typename CT>
__global__ __launch_bounds__(256, 2)
void gemm128(const AT* __restrict__ A, const ushort* __restrict__ Bt,
             const float* __restrict__ bias, const float* __restrict__ resid,
             CT* __restrict__ C)
{
    constexpr int K = 2048, N = 2048;
    __shared__ alignas(16) ushort lA[128 * 32];
    __shared__ alignas(16) ushort lB[128 * 32];

    const int t = threadIdx.x;
    const int wave = t >> 6, lane = t & 63;
    const int row0 = blockIdx.y * 128, col0 = blockIdx.x * 128;

    // staging: thread t owns 8-elem chunk -> tile row t/4, cols (t%4)*8..+7
    const int sr = t >> 2, sc = (t & 3) * 8;
    const AT* gA0 = A + (size_t)(row0 + sr) * K + sc;
    const AT* gA1 = A + (size_t)(row0 + 64 + sr) * K + sc;
    const ushort* gB0 = Bt + (size_t)(col0 + sr) * K + sc;
    const ushort* gB1 = Bt + (size_t)(col0 + 64 + sr) * K + sc;

    const int wm = (wave >> 1) * 64;
    const int wn = (wave & 1) * 64;
    const int q4 = lane >> 4;
    const int lr = lane & 15;

    floatx4 acc[4][4];
    #pragma unroll
    for (int i = 0; i < 4; i++)
        #pragma unroll
        for (int j = 0; j < 4; j++)
            acc[i][j] = (floatx4){0.f, 0.f, 0.f, 0.f};

    for (int kt = 0; kt < K / 32; ++kt) {
        const int ko = kt * 32;
        short8 ra0, ra1, rb0, rb1;
        if constexpr (__is_same(AT, float)) {
            const float* p0 = gA0 + ko;
            const float* p1 = gA1 + ko;
            ra0 = pack8(*(const floatx4*)p0, *(const floatx4*)(p0 + 4));
            ra1 = pack8(*(const floatx4*)p1, *(const floatx4*)(p1 + 4));
        } else {
            ra0 = *(const short8*)(gA0 + ko);
            ra1 = *(const short8*)(gA1 + ko);
        }
        rb0 = *(const short8*)(gB0 + ko);
        rb1 = *(const short8*)(gB1 + ko);

        __syncthreads();   // previous iteration's LDS reads complete
        *(short8*)&lA[t * 8]        = ra0;
        *(short8*)&lA[2048 + t * 8] = ra1;
        *(short8*)&lB[t * 8]        = rb0;
        *(short8*)&lB[2048 + t * 8] = rb1;
        __syncthreads();   // tiles visible

        short8 af[4], bfr[4];
        #pragma unroll
        for (int i = 0; i < 4; i++)
            af[i] = *(const short8*)&lA[(wm + i * 16 + lr) * 32 + q4 * 8];
        #pragma unroll
        for (int j = 0; j < 4; j++)
            bfr[j] = *(const short8*)&lB[(wn + j * 16 + lr) * 32 + q4 * 8];

        #pragma unroll
        for (int i = 0; i < 4; i++)
            #pragma unroll
            for (int j = 0; j < 4; j++)
                acc[i][j] = __builtin_amdgcn_mfma_f32_16x16x32_bf16(
                    af[i], bfr[j], acc[i][j], 0, 0, 0);
    }

    // epilogue: D[row=quad*4+reg][col=lane&15]  (m89-verified mapping)
    #pragma unroll
    for (int j = 0; j < 4; j++) {
        const int gcol = col0 + wn + j * 16 + lr;
        const float bv = bias[gcol];
        #pragma unroll
        for (int i = 0; i < 4; i++) {
            #pragma unroll
            for (int r = 0; r < 4; r++) {
                const int grow = row0 + wm + i * 16 + q4 * 4 + r;
                const size_t off = (size_t)grow * N + gcol;
                float v = acc[i][j][r] + bv;
                if (resid) v += resid[off];
                if constexpr (__is_same(CT, float)) C[off] = v;
                else                                C[off] = f2bf(v);
            }
        }
    }
}

// -------- per-position attention: one wave per (b,s), bf16 in/out -----------
__global__ __launch_bounds__(256, 2)
void attn_kernel(ushort* __restrict__ q, const ushort* __restrict__ k,
                 const ushort* __restrict__ v)
{
    __shared__ alignas(16) ushort sq[4][2048];
    __shared__ alignas(16) ushort sk[4][2048];
    __shared__ alignas(16) ushort sv[4][2048];
    const int wave = threadIdx.x >> 6, lane = threadIdx.x & 63;
    const size_t p = (size_t)blockIdx.x * 4 + wave;
    const size_t base = p * 2048;

    #pragma unroll
    for (int c = 0; c < 4; c++) {
        const int idx = c * 512 + lane * 8;
        *(short8*)&sq[wave][idx] = *(const short8*)&q[base + idx];
        *(short8*)&sk[wave][idx] = *(const short8*)&k[base + idx];
        *(short8*)&sv[wave][idx] = *(const short8*)&v[base + idx];
    }

    const int h = lane >> 3;
    const int tt = lane & 7;
    float s = 0.f;
    #pragma unroll 4
    for (int c = 0; c < 32; c++) {
        short8 qv = *(const short8*)&sq[wave][h * 256 + c * 8];
        short8 kv = *(const short8*)&sk[wave][tt * 256 + c * 8];
        #pragma unroll
        for (int e = 0; e < 8; e++)
            s += bf2f((ushort)qv[e]) * bf2f((ushort)kv[e]);
    }
    s *= (1.0f / 16.0f);   // 1/sqrt(256)

    float m = s;
    m = fmaxf(m, __shfl_xor(m, 1));
    m = fmaxf(m, __shfl_xor(m, 2));
    m = fmaxf(m, __shfl_xor(m, 4));
    float e = __expf(s - m);
    float sum = e;
    sum += __shfl_xor(sum, 1);
    sum += __shfl_xor(sum, 2);
    sum += __shfl_xor(sum, 4);
    const float w = e / sum;

    float wt[8];
    #pragma unroll
    for (int t2 = 0; t2 < 8; t2++)
        wt[t2] = __shfl(w, (lane & 56) + t2);

    const int d0 = (lane & 7) * 8;
    #pragma unroll
    for (int c = 0; c < 4; c++) {
        const int d = d0 + c * 64;
        float acc[8] = {0, 0, 0, 0, 0, 0, 0, 0};
        #pragma unroll
        for (int t2 = 0; t2 < 8; t2++) {
            short8 vv = *(const short8*)&sv[wave][t2 * 256 + d];
            #pragma unroll
            for (int e2 = 0; e2 < 8; e2++)
                acc[e2] += wt[t2] * bf2f((ushort)vv[e2]);
        }
        short8 o;
        #pragma unroll
        for (int e2 = 0; e2 < 8; e2++)
            o[e2] = (short)f2bf(acc[e2]);
        *(short8*)&q[base + h * 256 + d] = o;
    }
}

// -------- LayerNorm over C=2048, fp32 in place on d_out ---------------------
__global__ __launch_bounds__(256, 2)
void ln_kernel(float* __restrict__ y, const float* __restrict__ gamma,
               const float* __restrict__ beta)
{
    __shared__ float red[2][4];
    const int t = threadIdx.x;
    const size_t base = (size_t)blockIdx.x * 2048 + t * 8;
    floatx4 a = *(const floatx4*)&y[base];
    floatx4 b = *(const floatx4*)&y[base + 4];
    float f[8] = {a[0], a[1], a[2], a[3], b[0], b[1], b[2], b[3]};
    float s = 0.f, ss = 0.f;
    #pragma unroll
    for (int e = 0; e < 8; e++) { s += f[e]; ss += f[e] * f[e]; }
    #pragma unroll
    for (int off = 1; off < 64; off <<= 1) {
        s  += __shfl_xor(s, off);
        ss += __shfl_xor(ss, off);
    }
    const int wave = t >> 6, lane = t & 63;
    if (lane == 0) { red[0][wave] = s; red[1][wave] = ss; }
    __syncthreads();
    s  = red[0][0] + red[0][1] + red[0][2] + red[0][3];
    ss = red[1][0] + red[1][1] + red[1][2] + red[1][3];
    const float mu  = s * (1.f / 2048.f);
    const float var = fmaxf(ss * (1.f / 2048.f) - mu * mu, 0.f);
    const float rs  = rsqrtf(var + 1e-5f);
    floatx4 g0 = *(const floatx4*)&gamma[t * 8];
    floatx4 g1 = *(const floatx4*)&gamma[t * 8 + 4];
    floatx4 b0 = *(const floatx4*)&beta[t * 8];
    floatx4 b1 = *(const floatx4*)&beta[t * 8 + 4];
    floatx4 o0, o1;
    #pragma unroll
    for (int e = 0; e < 4; e++) {
        o0[e] = g0[e] * (f[e] - mu) * rs + b0[e];
        o1[e] = g1[e] * (f[e + 4] - mu) * rs + b1[e];
    }
    *(floatx4*)&y[base]     = o0;
    *(floatx4*)&y[base + 4] = o1;
}

extern "C" void kernel_launch(void* const* d_in, const int* in_sizes, int n_in,
                              void* d_out, int out_size, void* d_ws, size_t ws_size,
                              hipStream_t stream)
{
    const float* x     = (const float*)d_in[0];
    const float* Wq    = (const float*)d_in[1];
    const float* bq    = (const float*)d_in[2];
    const float* Wk    = (const float*)d_in[3];
    const float* bk    = (const float*)d_in[4];
    const float* Wv    = (const float*)d_in[5];
    const float* bv    = (const float*)d_in[6];
    const float* Wo    = (const float*)d_in[7];
    const float* bo    = (const float*)d_in[8];
    const float* gamma = (const float*)d_in[9];
    const float* beta  = (const float*)d_in[10];
    float* out = (float*)d_out;

    char* ws = (char*)d_ws;
    const size_t MB = 1024 * 1024;
    ushort* WqT = (ushort*)(ws + 0 * MB);
    ushort* WkT = (ushort*)(ws + 8 * MB);
    ushort* WvT = (ushort*)(ws + 16 * MB);
    ushort* WoT = (ushort*)(ws + 24 * MB);
    ushort* q   = (ushort*)(ws + 32 * MB);    // 64MB bf16; attended overwrites
    ushort* k   = (ushort*)(ws + 96 * MB);    // 64MB bf16
    ushort* v   = (ushort*)(ws + 160 * MB);   // 64MB bf16

    dim3 tb(32, 8), tg(64, 64);
    convT2048<<<tg, tb, 0, stream>>>(Wq, WqT);
    convT2048<<<tg, tb, 0, stream>>>(Wk, WkT);
    convT2048<<<tg, tb, 0, stream>>>(Wv, WvT);
    convT2048<<<tg, tb, 0, stream>>>(Wo, WoT);

    dim3 gg(16, 128);   // N-tiles x M-tiles
    gemm128<float, ushort><<<gg, 256, 0, stream>>>(x, WqT, bq, nullptr, q);
    gemm128<float, ushort><<<gg, 256, 0, stream>>>(x, WkT, bk, nullptr, k);
    gemm128<float, ushort><<<gg, 256, 0, stream>>>(x, WvT, bv, nullptr, v);

    attn_kernel<<<4096, 256, 0, stream>>>(q, k, v);

    gemm128<ushort, float><<<gg, 256, 0, stream>>>(q, WoT, bo, x, out);

    ln_kernel<<<16384, 256, 0, stream>>>(out, gamma, beta);
}

// Round 4
// 1143.914 us; speedup vs baseline: 1.1289x; 1.1289x over previous
//
#include <hip/hip_runtime.h>
#include <hip/hip_bf16.h>
#include <stdint.h>

// SelfAttentionBlock: B=4,S=4096,C=2048,O=2048,H=8,DH=256
// Inputs/outputs fp32; internal bf16 MFMA (m97-structure GEMMs w/ global_load_lds).
//
// Pipeline (path X, ws >= 288MB):
//   0) x (fp32) -> xbf (bf16, 64MB ws)
//   1) transpose+convert W* -> bf16 [N][K]
//   2) q,k,v = xbf @ W + b        (gemm_bt, bf16 A, global_load_lds)
//   3) per-position 8-head attention, attended overwrites q
//   4) y = attended @ Wo + bo + x -> d_out (fp32)   (gemm_bt, fp32 out + resid)
//   5) LayerNorm in place on d_out
// Path Y (ws < 288MB): QKV GEMMs use gemm_f32a (fp32 A staged raw via
// global_load_lds, cvt after ds_read); rest identical.
//
// ws: WT 0..32MB | q 32..96 | k 96..160 | v 160..224 | xbf 224..288

using short8  = __attribute__((ext_vector_type(8))) short;
using floatx4 = __attribute__((ext_vector_type(4))) float;

__device__ __forceinline__ float bf2f(ushort u) {
    union { uint32_t i; float f; } v; v.i = ((uint32_t)u) << 16; return v.f;
}
__device__ __forceinline__ ushort f2bf(float f) {
    union { float f; uint32_t i; } v; v.f = f;
    uint32_t r = v.i + 0x7fffu + ((v.i >> 16) & 1u);
    return (ushort)(r >> 16);
}
__device__ __forceinline__ short8 pack8(const floatx4& a, const floatx4& b) {
    short8 o;
    o[0] = (short)f2bf(a[0]); o[1] = (short)f2bf(a[1]);
    o[2] = (short)f2bf(a[2]); o[3] = (short)f2bf(a[3]);
    o[4] = (short)f2bf(b[0]); o[5] = (short)f2bf(b[1]);
    o[6] = (short)f2bf(b[2]); o[7] = (short)f2bf(b[3]);
    return o;
}
__device__ __forceinline__ void async_copy16(const void* g, void* l) {
    __builtin_amdgcn_global_load_lds(
        (__attribute__((address_space(1))) uint32_t*)g,
        (__attribute__((address_space(3))) uint32_t*)l,
        16, 0, 0);
}

// -------- fp32 -> bf16 bulk convert (8 elems/thread) ------------------------
__global__ void cvt_bf16(const float* __restrict__ in, ushort* __restrict__ out) {
    const size_t base = ((size_t)blockIdx.x * 256 + threadIdx.x) * 8;
    floatx4 a = *(const floatx4*)&in[base];
    floatx4 b = *(const floatx4*)&in[base + 4];
    *(short8*)&out[base] = pack8(a, b);
}

// -------- weight transpose+convert: fp32 [2048][2048] -> bf16 T -------------
__global__ void convT2048(const float* __restrict__ in, ushort* __restrict__ out) {
    __shared__ alignas(16) float tile[32][33];
    const int x = blockIdx.x * 32 + threadIdx.x;
    const int y0 = blockIdx.y * 32;
    for (int j = threadIdx.y; j < 32; j += 8)
        tile[j][threadIdx.x] = in[(size_t)(y0 + j) * 2048 + x];
    __syncthreads();
    const int x2 = blockIdx.y * 32 + threadIdx.x;
    const int y2 = blockIdx.x * 32;
    for (int j = threadIdx.y; j < 32; j += 8)
        out[(size_t)(y2 + j) * 2048 + x2] = f2bf(tile[threadIdx.x][j]);
}

// -------- m97 GEMM: C[M][2048] = A_bf16[M][2048] @ Bt^T + bias (+resid) -----
// 128x128 tile, BK=32, 4 waves x (4x4) 16x16x32 MFMA, global_load_lds w=16.
template <typename CT>
__global__ __launch_bounds__(256, 2)
void gemm_bt(const ushort* __restrict__ A, const ushort* __restrict__ Bt,
             const float* __restrict__ bias, const float* __restrict__ resid,
             CT* __restrict__ C)
{
    constexpr int K = 2048, N = 2048;
    __shared__ alignas(16) ushort lA[128 * 32];
    __shared__ alignas(16) ushort lB[128 * 32];

    const int t = threadIdx.x;
    const int wave = t >> 6, lane = t & 63;
    const int row0 = blockIdx.y * 128, col0 = blockIdx.x * 128;

    // staging: thread t owns 16B -> tile row t/4, cols (t%4)*8..+7
    // LDS linear t*8 = wave-uniform base (wave*512) + lane*8  (DMA-compatible)
    const int sr = t >> 2, sc = (t & 3) * 8;
    const ushort* gA0 = A + (size_t)(row0 + sr) * K + sc;
    const ushort* gA1 = A + (size_t)(row0 + 64 + sr) * K + sc;
    const ushort* gB0 = Bt + (size_t)(col0 + sr) * K + sc;
    const ushort* gB1 = Bt + (size_t)(col0 + 64 + sr) * K + sc;
    ushort* lA0 = &lA[t * 8];
    ushort* lA1 = &lA[2048 + t * 8];
    ushort* lB0 = &lB[t * 8];
    ushort* lB1 = &lB[2048 + t * 8];

    const int wm = (wave >> 1) * 64;
    const int wn = (wave & 1) * 64;
    const int q4 = lane >> 4;
    const int lr = lane & 15;

    floatx4 acc[4][4];
    #pragma unroll
    for (int i = 0; i < 4; i++)
        #pragma unroll
        for (int j = 0; j < 4; j++)
            acc[i][j] = (floatx4){0.f, 0.f, 0.f, 0.f};

    for (int kt = 0; kt < K / 32; ++kt) {
        const int ko = kt * 32;
        async_copy16(gA0 + ko, lA0);
        async_copy16(gA1 + ko, lA1);
        async_copy16(gB0 + ko, lB0);
        async_copy16(gB1 + ko, lB1);
        __syncthreads();   // drains vmcnt(0): DMA landed, all waves' prior reads done

        short8 af[4], bfr[4];
        #pragma unroll
        for (int i = 0; i < 4; i++)
            af[i] = *(const short8*)&lA[(wm + i * 16 + lr) * 32 + q4 * 8];
        #pragma unroll
        for (int j = 0; j < 4; j++)
            bfr[j] = *(const short8*)&lB[(wn + j * 16 + lr) * 32 + q4 * 8];

        #pragma unroll
        for (int i = 0; i < 4; i++)
            #pragma unroll
            for (int j = 0; j < 4; j++)
                acc[i][j] = __builtin_amdgcn_mfma_f32_16x16x32_bf16(
                    af[i], bfr[j], acc[i][j], 0, 0, 0);
        __syncthreads();   // all reads retired before next iter's DMA overwrites
    }

    // epilogue: D[row=quad*4+reg][col=lane&15]
    #pragma unroll
    for (int j = 0; j < 4; j++) {
        const int gcol = col0 + wn + j * 16 + lr;
        const float bv = bias[gcol];
        #pragma unroll
        for (int i = 0; i < 4; i++) {
            #pragma unroll
            for (int r = 0; r < 4; r++) {
                const int grow = row0 + wm + i * 16 + q4 * 4 + r;
                const size_t off = (size_t)grow * N + gcol;
                float v = acc[i][j][r] + bv;
                if (resid) v += resid[off];
                if constexpr (__is_same(CT, float)) C[off] = v;
                else                                C[off] = f2bf(v);
            }
        }
    }
}

// -------- fallback GEMM: fp32 A staged raw via global_load_lds, cvt in regs -
__global__ __launch_bounds__(256, 2)
void gemm_f32a(const float* __restrict__ A, const ushort* __restrict__ Bt,
               const float* __restrict__ bias, ushort* __restrict__ C)
{
    constexpr int K = 2048, N = 2048;
    __shared__ alignas(16) float  lA32[128 * 32];   // 16KB
    __shared__ alignas(16) ushort lB[128 * 32];     // 8KB

    const int t = threadIdx.x;
    const int wave = t >> 6, lane = t & 63;
    const int row0 = blockIdx.y * 128, col0 = blockIdx.x * 128;

    // A staging: chunk c = n*256+t -> row c/8, cols (c%8)*4..+3 (fp32, 16B)
    const int ar = t >> 3, ac = (t & 7) * 4;
    const float* gA0 = A + (size_t)(row0 + ar) * K + ac;
    const ushort* gB0 = Bt + (size_t)(col0 + (t >> 2)) * K + (t & 3) * 8;
    const ushort* gB1 = Bt + (size_t)(col0 + 64 + (t >> 2)) * K + (t & 3) * 8;

    const int wm = (wave >> 1) * 64;
    const int wn = (wave & 1) * 64;
    const int q4 = lane >> 4;
    const int lr = lane & 15;

    floatx4 acc[4][4];
    #pragma unroll
    for (int i = 0; i < 4; i++)
        #pragma unroll
        for (int j = 0; j < 4; j++)
            acc[i][j] = (floatx4){0.f, 0.f, 0.f, 0.f};

    for (int kt = 0; kt < K / 32; ++kt) {
        const int ko = kt * 32;
        #pragma unroll
        for (int n = 0; n < 4; n++)
            async_copy16(gA0 + (size_t)n * 32 * K + ko, &lA32[(n * 256 + t) * 4]);
        async_copy16(gB0 + ko, &lB[t * 8]);
        async_copy16(gB1 + ko, &lB[2048 + t * 8]);
        __syncthreads();

        short8 af[4], bfr[4];
        #pragma unroll
        for (int i = 0; i < 4; i++) {
            const floatx4* pa = (const floatx4*)&lA32[(wm + i * 16 + lr) * 32 + q4 * 8];
            af[i] = pack8(pa[0], pa[1]);
        }
        #pragma unroll
        for (int j = 0; j < 4; j++)
            bfr[j] = *(const short8*)&lB[(wn + j * 16 + lr) * 32 + q4 * 8];

        #pragma unroll
        for (int i = 0; i < 4; i++)
            #pragma unroll
            for (int j = 0; j < 4; j++)
                acc[i][j] = __builtin_amdgcn_mfma_f32_16x16x32_bf16(
                    af[i], bfr[j], acc[i][j], 0, 0, 0);
        __syncthreads();
    }

    #pragma unroll
    for (int j = 0; j < 4; j++) {
        const int gcol = col0 + wn + j * 16 + lr;
        const float bv = bias[gcol];
        #pragma unroll
        for (int i = 0; i < 4; i++)
            #pragma unroll
            for (int r = 0; r < 4; r++) {
                const int grow = row0 + wm + i * 16 + q4 * 4 + r;
                C[(size_t)grow * N + gcol] = f2bf(acc[i][j][r] + bv);
            }
    }
}

// -------- per-position attention: one wave per (b,s), bf16 in/out -----------
__global__ __launch_bounds__(256, 2)
void attn_kernel(ushort* __restrict__ q, const ushort* __restrict__ k,
                 const ushort* __restrict__ v)
{
    __shared__ alignas(16) ushort sq[4][2048];
    __shared__ alignas(16) ushort sk[4][2048];
    __shared__ alignas(16) ushort sv[4][2048];
    const int wave = threadIdx.x >> 6, lane = threadIdx.x & 63;
    const size_t p = (size_t)blockIdx.x * 4 + wave;
    const size_t base = p * 2048;

    #pragma unroll
    for (int c = 0; c < 4; c++) {
        const int idx = c * 512 + lane * 8;
        *(short8*)&sq[wave][idx] = *(const short8*)&q[base + idx];
        *(short8*)&sk[wave][idx] = *(const short8*)&k[base + idx];
        *(short8*)&sv[wave][idx] = *(const short8*)&v[base + idx];
    }

    const int h = lane >> 3;
    const int tt = lane & 7;
    float s = 0.f;
    #pragma unroll 4
    for (int c = 0; c < 32; c++) {
        short8 qv = *(const short8*)&sq[wave][h * 256 + c * 8];
        short8 kv = *(const short8*)&sk[wave][tt * 256 + c * 8];
        #pragma unroll
        for (int e = 0; e < 8; e++)
            s += bf2f((ushort)qv[e]) * bf2f((ushort)kv[e]);
    }
    s *= (1.0f / 16.0f);   // 1/sqrt(256)

    float m = s;
    m = fmaxf(m, __shfl_xor(m, 1));
    m = fmaxf(m, __shfl_xor(m, 2));
    m = fmaxf(m, __shfl_xor(m, 4));
    float e = __expf(s - m);
    float sum = e;
    sum += __shfl_xor(sum, 1);
    sum += __shfl_xor(sum, 2);
    sum += __shfl_xor(sum, 4);
    const float w = e / sum;

    float wt[8];
    #pragma unroll
    for (int t2 = 0; t2 < 8; t2++)
        wt[t2] = __shfl(w, (lane & 56) + t2);

    const int d0 = (lane & 7) * 8;
    #pragma unroll
    for (int c = 0; c < 4; c++) {
        const int d = d0 + c * 64;
        float acc[8] = {0, 0, 0, 0, 0, 0, 0, 0};
        #pragma unroll
        for (int t2 = 0; t2 < 8; t2++) {
            short8 vv = *(const short8*)&sv[wave][t2 * 256 + d];
            #pragma unroll
            for (int e2 = 0; e2 < 8; e2++)
                acc[e2] += wt[t2] * bf2f((ushort)vv[e2]);
        }
        short8 o;
        #pragma unroll
        for (int e2 = 0; e2 < 8; e2++)
            o[e2] = (short)f2bf(acc[e2]);
        *(short8*)&q[base + h * 256 + d] = o;
    }
}

// -------- LayerNorm over C=2048, fp32 in place on d_out ---------------------
__global__ __launch_bounds__(256, 2)
void ln_kernel(float* __restrict__ y, const float* __restrict__ gamma,
               const float* __restrict__ beta)
{
    __shared__ float red[2][4];
    const int t = threadIdx.x;
    const size_t base = (size_t)blockIdx.x * 2048 + t * 8;
    floatx4 a = *(const floatx4*)&y[base];
    floatx4 b = *(const floatx4*)&y[base + 4];
    float f[8] = {a[0], a[1], a[2], a[3], b[0], b[1], b[2], b[3]};
    float s = 0.f, ss = 0.f;
    #pragma unroll
    for (int e = 0; e < 8; e++) { s += f[e]; ss += f[e] * f[e]; }
    #pragma unroll
    for (int off = 1; off < 64; off <<= 1) {
        s  += __shfl_xor(s, off);
        ss += __shfl_xor(ss, off);
    }
    const int wave = t >> 6, lane = t & 63;
    if (lane == 0) { red[0][wave] = s; red[1][wave] = ss; }
    __syncthreads();
    s  = red[0][0] + red[0][1] + red[0][2] + red[0][3];
    ss = red[1][0] + red[1][1] + red[1][2] + red[1][3];
    const float mu  = s * (1.f / 2048.f);
    const float var = fmaxf(ss * (1.f / 2048.f) - mu * mu, 0.f);
    const float rs  = rsqrtf(var + 1e-5f);
    floatx4 g0 = *(const floatx4*)&gamma[t * 8];
    floatx4 g1 = *(const floatx4*)&gamma[t * 8 + 4];
    floatx4 b0 = *(const floatx4*)&beta[t * 8];
    floatx4 b1 = *(const floatx4*)&beta[t * 8 + 4];
    floatx4 o0, o1;
    #pragma unroll
    for (int e = 0; e < 4; e++) {
        o0[e] = g0[e] * (f[e] - mu) * rs + b0[e];
        o1[e] = g1[e] * (f[e + 4] - mu) * rs + b1[e];
    }
    *(floatx4*)&y[base]     = o0;
    *(floatx4*)&y[base + 4] = o1;
}

extern "C" void kernel_launch(void* const* d_in, const int* in_sizes, int n_in,
                              void* d_out, int out_size, void* d_ws, size_t ws_size,
                              hipStream_t stream)
{
    const float* x     = (const float*)d_in[0];
    const float* Wq    = (const float*)d_in[1];
    const float* bq    = (const float*)d_in[2];
    const float* Wk    = (const float*)d_in[3];
    const float* bk    = (const float*)d_in[4];
    const float* Wv    = (const float*)d_in[5];
    const float* bv    = (const float*)d_in[6];
    const float* Wo    = (const float*)d_in[7];
    const float* bo    = (const float*)d_in[8];
    const float* gamma = (const float*)d_in[9];
    const float* beta  = (const float*)d_in[10];
    float* out = (float*)d_out;

    char* ws = (char*)d_ws;
    const size_t MB = 1024 * 1024;
    ushort* WqT = (ushort*)(ws + 0 * MB);
    ushort* WkT = (ushort*)(ws + 8 * MB);
    ushort* WvT = (ushort*)(ws + 16 * MB);
    ushort* WoT = (ushort*)(ws + 24 * MB);
    ushort* q   = (ushort*)(ws + 32 * MB);    // 64MB bf16; attended overwrites
    ushort* k   = (ushort*)(ws + 96 * MB);    // 64MB bf16
    ushort* v   = (ushort*)(ws + 160 * MB);   // 64MB bf16
    ushort* xbf = (ushort*)(ws + 224 * MB);   // 64MB bf16 (path X only)

    const bool bigws = ws_size >= 288 * MB;

    dim3 tb(32, 8), tg(64, 64);
    convT2048<<<tg, tb, 0, stream>>>(Wq, WqT);
    convT2048<<<tg, tb, 0, stream>>>(Wk, WkT);
    convT2048<<<tg, tb, 0, stream>>>(Wv, WvT);
    convT2048<<<tg, tb, 0, stream>>>(Wo, WoT);

    dim3 gg(16, 128);   // N-tiles x M-tiles
    if (bigws) {
        cvt_bf16<<<16384, 256, 0, stream>>>(x, xbf);
        gemm_bt<ushort><<<gg, 256, 0, stream>>>(xbf, WqT, bq, nullptr, q);
        gemm_bt<ushort><<<gg, 256, 0, stream>>>(xbf, WkT, bk, nullptr, k);
        gemm_bt<ushort><<<gg, 256, 0, stream>>>(xbf, WvT, bv, nullptr, v);
    } else {
        gemm_f32a<<<gg, 256, 0, stream>>>(x, WqT, bq, q);
        gemm_f32a<<<gg, 256, 0, stream>>>(x, WkT, bk, k);
        gemm_f32a<<<gg, 256, 0, stream>>>(x, WvT, bv, v);
    }

    attn_kernel<<<4096, 256, 0, stream>>>(q, k, v);

    gemm_bt<float><<<gg, 256, 0, stream>>>(q, WoT, bo, x, out);

    ln_kernel<<<16384, 256, 0, stream>>>(out, gamma, beta);
}